// Round 1
// baseline (623.367 us; speedup 1.0000x reference)
//
#include <hip/hip_runtime.h>
#include <hip/hip_bf16.h>

typedef __attribute__((ext_vector_type(8))) short short8;
typedef __attribute__((ext_vector_type(4))) float f32x4;

__device__ __forceinline__ float relu_(float x){ return fmaxf(x, 0.f); }

__device__ __forceinline__ unsigned short f2b(float x){
  __hip_bfloat16 h = __float2bfloat16(x);
  union { __hip_bfloat16 h; unsigned short u; } cv;
  cv.h = h; return cv.u;
}

// ---------------- workspace layout (bytes) ----------------
#define OFF_SBA    0            // 150 f32 (scale,bias per cj) for Angle BN
#define OFF_SBD    1024         // 150 f32 for dif BN
#define OFF_SPA    2048         // spa embed [25][64] f32
#define OFF_W2AT   8704         // je_w2 transposed [c][o] f32 (16KB)
#define OFF_W2DT   25088        // df_w2 transposed (16KB)
#define OFF_BN2SB  41472        // BN2 (scale,bias) [256][2] f32
#define OFF_W1B    43520        // g1_w bf16 [256][128]
#define OFF_W2B    (43520 + 65536)
#define OFF_WGB    (43520 + 131072)
#define OFF_WG1B   (43520 + 196608)
#define OFF_PART   305664       // partials [2048][512] f32 (4MB)
#define OFF_EXT    (305664 + 4194304)            // ext f32 [16384][256] (16.8MB)
#define OFF_INP    (305664 + 4194304 + 16777216) // inp bf16 [16384][25][128] (104.9MB)

// ---------------- prep: weights -> bf16, embed W2 transposes ----------------
__global__ void kprep(const float* __restrict__ g1_w, const float* __restrict__ g2_w,
                      const float* __restrict__ gw,  const float* __restrict__ gw1,
                      const float* __restrict__ je_w2, const float* __restrict__ df_w2,
                      __hip_bfloat16* W1, __hip_bfloat16* W2,
                      __hip_bfloat16* WG, __hip_bfloat16* WG1,
                      float* w2aT, float* w2dT)
{
  int stride = gridDim.x * blockDim.x;
  for (int i = blockIdx.x*blockDim.x + threadIdx.x; i < 32768; i += stride){
    W1[i]  = __float2bfloat16(g1_w[i]);
    W2[i]  = __float2bfloat16(g2_w[i]);
    WG[i]  = __float2bfloat16(gw[i]);
    WG1[i] = __float2bfloat16(gw1[i]);
  }
  for (int i = blockIdx.x*blockDim.x + threadIdx.x; i < 4096; i += stride){
    int o = i >> 6, c = i & 63;
    w2aT[c*64 + o] = je_w2[i];
    w2dT[c*64 + o] = df_w2[i];
  }
}

// ---------------- spa embed: [25][64], t/b invariant ----------------
__global__ void kspa(const float* __restrict__ w1, const float* __restrict__ b1,
                     const float* __restrict__ w2, const float* __restrict__ b2,
                     const float* __restrict__ spa, float* spa_arr)
{
  __shared__ float r[64][26];
  int tid = threadIdx.x;
  for (int i = tid; i < 1600; i += 256){
    int o = i/25, j = i%25;
    float acc = b1[o];
    for (int c = 0; c < 25; ++c) acc += w1[o*25 + c] * spa[c*25 + j];
    r[o][j] = fmaxf(acc, 0.f);
  }
  __syncthreads();
  for (int i = tid; i < 1600; i += 256){
    int j = i >> 6, o2 = i & 63;   // i<1600 -> j<25
    float acc = b2[o2];
    for (int c = 0; c < 64; ++c) acc += w2[o2*64 + c] * r[c][j];
    spa_arr[j*64 + o2] = fmaxf(acc, 0.f);
  }
}

// ---------------- BN1 stats: per channel cj over (b,t) ----------------
__global__ void kbn1(const float* __restrict__ Angle, const float* __restrict__ dif,
                     const float* __restrict__ ga, const float* __restrict__ ba,
                     const float* __restrict__ gd, const float* __restrict__ bd,
                     float* sbA, float* sbD)
{
  __shared__ float red[256];
  __shared__ float red2[256];
  int blk = blockIdx.x;
  int which = blk / 75, cj = blk % 75;
  const float* x = which ? dif : Angle;
  int tid = threadIdx.x;
  float s = 0.f, q = 0.f;
  for (int i = tid; i < 16384; i += 256){
    int b = i >> 9, t = i & 511;
    float v = x[((size_t)b*75 + cj)*512 + t];
    s += v; q += v*v;
  }
  red[tid] = s; red2[tid] = q;
  __syncthreads();
  for (int off = 128; off > 0; off >>= 1){
    if (tid < off){ red[tid] += red[tid+off]; red2[tid] += red2[tid+off]; }
    __syncthreads();
  }
  if (tid == 0){
    float m = red[0] * (1.f/16384.f);
    float v = red2[0] * (1.f/16384.f) - m*m;
    float rstd = rsqrtf(v + 1e-5f);
    float g = (which ? gd : ga)[cj];
    float be = (which ? bd : ba)[cj];
    float sc = g * rstd;
    float* dst = which ? sbD : sbA;
    dst[cj*2]   = sc;
    dst[cj*2+1] = be - m*sc;
  }
}

// ---------------- embed: BN + 3->64 conv + relu + 64->64 conv + relu, a+d, concat spa
// lane = t; per lane keeps 64+64 f32 accumulators; weights via uniform (scalar) loads.
__global__ __launch_bounds__(256, 2) void kembed(
    const float* __restrict__ Angle, const float* __restrict__ dif,
    const float* __restrict__ sbA, const float* __restrict__ sbD,
    const float* __restrict__ w1a, const float* __restrict__ b1a,
    const float* __restrict__ w2aT, const float* __restrict__ b2a,
    const float* __restrict__ w1d, const float* __restrict__ b1d,
    const float* __restrict__ w2dT, const float* __restrict__ b2d,
    const float* __restrict__ spa_arr, __hip_bfloat16* __restrict__ inp)
{
  int b = blockIdx.x, j = blockIdx.y, tc = blockIdx.z;
  int t = tc*256 + threadIdx.x;
  float xa[3], xd[3];
  #pragma unroll
  for (int cc = 0; cc < 3; ++cc){
    size_t off = ((size_t)(b*3+cc)*25 + j)*512 + t;
    int cj = cc*25 + j;
    xa[cc] = Angle[off]*sbA[2*cj] + sbA[2*cj+1];
    xd[cc] = dif[off]*sbD[2*cj] + sbD[2*cj+1];
  }
  float oa[64], od[64];
  #pragma unroll
  for (int o = 0; o < 64; ++o){ oa[o] = b2a[o]; od[o] = b2d[o]; }
  for (int c = 0; c < 64; ++c){
    float ha = fmaxf(b1a[c] + w1a[c*3]*xa[0] + w1a[c*3+1]*xa[1] + w1a[c*3+2]*xa[2], 0.f);
    float hd = fmaxf(b1d[c] + w1d[c*3]*xd[0] + w1d[c*3+1]*xd[1] + w1d[c*3+2]*xd[2], 0.f);
    const float* wa = w2aT + c*64;
    const float* wd = w2dT + c*64;
    #pragma unroll
    for (int o = 0; o < 64; ++o){
      oa[o] = fmaf(wa[o], ha, oa[o]);
      od[o] = fmaf(wd[o], hd, od[o]);
    }
  }
  unsigned short* inpp = (unsigned short*)inp;
  size_t base = ((size_t)(b*512 + t)*25 + j)*128;
  const float* sp = spa_arr + j*64;
  union { unsigned short us[8]; uint4 v; } pk;
  #pragma unroll
  for (int o = 0; o < 64; o += 8){
    #pragma unroll
    for (int k2 = 0; k2 < 8; ++k2)
      pk.us[k2] = f2b(fmaxf(oa[o+k2],0.f) + fmaxf(od[o+k2],0.f));
    *reinterpret_cast<uint4*>(inpp + base + o) = pk.v;
  }
  #pragma unroll
  for (int o = 0; o < 64; o += 8){
    #pragma unroll
    for (int k2 = 0; k2 < 8; ++k2) pk.us[k2] = f2b(sp[o+k2]);
    *reinterpret_cast<uint4*>(inpp + base + 64 + o) = pk.v;
  }
}

// ---------------- fused attention core ----------------
// LDS offsets (bytes). All row-major bf16 unless noted. XOR swizzle: colb ^= (row&7)<<4.
#define XS_OFF   0        // X   [32][128] bf16, stride 256B, swz
#define XST_OFF  8192     // X^T [128][40] bf16, stride 80B, no swz
#define QS_OFF   18432    // Q   [32][256] bf16, stride 512B, swz
#define KS_OFF   34816    // K   [32][256] bf16, stride 512B, swz
#define SF_OFF   51200    // S   [32][33]  f32,  stride 132B
#define GB_OFF   55424    // G   [32][40]  bf16, stride 80B
#define LDS_TOT  57984
#define XMS_OFF  QS_OFF   // XM  [32][128] bf16, stride 256B, swz (aliases Q)

__device__ __forceinline__ short8 ldfrag(const char* p){
  return *reinterpret_cast<const short8*>(p);
}

__global__ __launch_bounds__(512, 2) void kattn(
    const unsigned short* __restrict__ inp,   // bf16 [16384][25][128]
    const __hip_bfloat16* __restrict__ W1b, const __hip_bfloat16* __restrict__ W2b,
    const __hip_bfloat16* __restrict__ WGb, const __hip_bfloat16* __restrict__ WG1b,
    const float* __restrict__ g1_b, const float* __restrict__ g2_b,
    const float* __restrict__ gw1_b, const float* __restrict__ gbn_g,
    float* __restrict__ ext, float* __restrict__ partials)
{
  __shared__ char lds[LDS_TOT];
  const int tid  = threadIdx.x;
  const int lane = tid & 63;
  const int w    = tid >> 6;      // wave 0..7
  const int l15  = lane & 15;
  const int g    = lane >> 4;     // 0..3

  float bq[2], bk[2], bh[2]; bool sg[2]; int oc_[2];
  #pragma unroll
  for (int n = 0; n < 2; ++n){
    int oc = w*32 + n*16 + l15;
    oc_[n] = oc;
    bq[n] = g1_b[oc]; bk[n] = g2_b[oc]; bh[n] = gw1_b[oc];
    sg[n] = (gbn_g[oc] >= 0.f);
  }
  float rs[2] = {0.f, 0.f}, rq[2] = {0.f, 0.f};

  for (int it = 0; it < 8; ++it){
    int token = blockIdx.x*8 + it;
    const unsigned int* src = (const unsigned int*)(inp + (size_t)token*3200);

    // ---- load X: pass A coalesced -> Xs (swz, rows 25..31 zero) ----
    for (int idx = tid; idx < 2048; idx += 512){
      int j = idx >> 6, c2 = idx & 63;
      int jj = (j < 25) ? j : 0;
      unsigned int v = src[jj*64 + c2];
      if (j >= 25) v = 0u;
      *(unsigned int*)(lds + XS_OFF + j*256 + ((c2*4) ^ ((j&7)<<4))) = v;
    }
    // ---- pass B (L2-hot reread) -> XsT, cols 25..31 zero ----
    for (int idx = tid; idx < 2048; idx += 512){
      int j = idx & 31, c2 = idx >> 5;
      int jj = (j < 25) ? j : 0;
      unsigned int v = src[jj*64 + c2];
      if (j >= 25) v = 0u;
      *(unsigned short*)(lds + XST_OFF + (2*c2)*80   + j*2) = (unsigned short)(v & 0xffffu);
      *(unsigned short*)(lds + XST_OFF + (2*c2+1)*80 + j*2) = (unsigned short)(v >> 16);
    }
    __syncthreads();

    // ---- Q = X W1^T + b1 ; K = X W2^T + b2 ----
    f32x4 aq[2][2], ak[2][2];
    #pragma unroll
    for (int n = 0; n < 2; ++n)
      #pragma unroll
      for (int mt = 0; mt < 2; ++mt){
        f32x4 vq = {bq[n], bq[n], bq[n], bq[n]};
        f32x4 vk = {bk[n], bk[n], bk[n], bk[n]};
        aq[mt][n] = vq; ak[mt][n] = vk;
      }
    #pragma unroll
    for (int kk = 0; kk < 4; ++kk){
      int cb = (kk*64 + g*16) ^ ((l15&7)<<4);
      short8 xa[2];
      xa[0] = ldfrag(lds + XS_OFF + l15*256 + cb);
      xa[1] = ldfrag(lds + XS_OFF + (16+l15)*256 + cb);
      #pragma unroll
      for (int n = 0; n < 2; ++n){
        size_t wrow = (size_t)(w*32 + n*16 + l15)*128 + kk*32 + g*8;
        short8 w1f = *reinterpret_cast<const short8*>(W1b + wrow);
        short8 w2f = *reinterpret_cast<const short8*>(W2b + wrow);
        #pragma unroll
        for (int mt = 0; mt < 2; ++mt){
          aq[mt][n] = __builtin_amdgcn_mfma_f32_16x16x32_bf16(xa[mt], w1f, aq[mt][n], 0, 0, 0);
          ak[mt][n] = __builtin_amdgcn_mfma_f32_16x16x32_bf16(xa[mt], w2f, ak[mt][n], 0, 0, 0);
        }
      }
    }
    #pragma unroll
    for (int n = 0; n < 2; ++n){
      int colb = oc_[n]*2;
      #pragma unroll
      for (int mt = 0; mt < 2; ++mt)
        #pragma unroll
        for (int r = 0; r < 4; ++r){
          int row = mt*16 + g*4 + r;
          int cb2 = colb ^ ((row&7)<<4);
          *(unsigned short*)(lds + QS_OFF + row*512 + cb2) = f2b(aq[mt][n][r]);
          *(unsigned short*)(lds + KS_OFF + row*512 + cb2) = f2b(ak[mt][n][r]);
        }
    }
    __syncthreads();

    // ---- S = Q K^T (waves 0..3) ----
    if (w < 4){
      int mt = w >> 1, nt = w & 1;
      f32x4 as = {0.f, 0.f, 0.f, 0.f};
      #pragma unroll
      for (int kk = 0; kk < 8; ++kk){
        int cb = (kk*64 + g*16) ^ ((l15&7)<<4);
        short8 qa = ldfrag(lds + QS_OFF + (mt*16 + l15)*512 + cb);
        short8 kb = ldfrag(lds + KS_OFF + (nt*16 + l15)*512 + cb);
        as = __builtin_amdgcn_mfma_f32_16x16x32_bf16(qa, kb, as, 0, 0, 0);
      }
      #pragma unroll
      for (int r = 0; r < 4; ++r){
        int row = mt*16 + g*4 + r;
        *(float*)(lds + SF_OFF + row*132 + (nt*16 + l15)*4) = as[r];
      }
    }
    __syncthreads();

    // ---- softmax over j' < 25, rows j < 25; G padded with zeros ----
    if (tid < 32){
      int row = tid;
      unsigned short* grow = (unsigned short*)(lds + GB_OFF + row*80);
      if (row < 25){
        const float* srow = (const float*)(lds + SF_OFF + row*132);
        float m = srow[0];
        #pragma unroll
        for (int c = 1; c < 25; ++c) m = fmaxf(m, srow[c]);
        float e[25]; float s = 0.f;
        #pragma unroll
        for (int c = 0; c < 25; ++c){ e[c] = __expf(srow[c] - m); s += e[c]; }
        float inv = 1.f / s;
        #pragma unroll
        for (int c = 0; c < 25; ++c) grow[c] = f2b(e[c]*inv);
        #pragma unroll
        for (int c = 25; c < 32; ++c) grow[c] = 0;
      } else {
        #pragma unroll
        for (int c = 0; c < 32; ++c) grow[c] = 0;
      }
    }
    __syncthreads();

    // ---- XM = G X  (wave w owns c-tile w*16..w*16+15) ----
    f32x4 am[2];
    {
      short8 bx = ldfrag(lds + XST_OFF + (w*16 + l15)*80 + g*16);
      #pragma unroll
      for (int mt = 0; mt < 2; ++mt){
        short8 ga = ldfrag(lds + GB_OFF + (mt*16 + l15)*80 + g*16);
        f32x4 z = {0.f, 0.f, 0.f, 0.f};
        am[mt] = __builtin_amdgcn_mfma_f32_16x16x32_bf16(ga, bx, z, 0, 0, 0);
      }
    }
    #pragma unroll
    for (int mt = 0; mt < 2; ++mt)
      #pragma unroll
      for (int r = 0; r < 4; ++r){
        int row = mt*16 + g*4 + r;
        int cb = ((w*16 + l15)*2) ^ ((row&7)<<4);
        *(unsigned short*)(lds + XMS_OFF + row*256 + cb) = f2b(am[mt][r]);
      }
    __syncthreads();

    // ---- H = XM gw^T + X gw1^T + gw1_b ----
    f32x4 ah[2][2];
    #pragma unroll
    for (int n = 0; n < 2; ++n)
      #pragma unroll
      for (int mt = 0; mt < 2; ++mt){
        f32x4 vb = {bh[n], bh[n], bh[n], bh[n]};
        ah[mt][n] = vb;
      }
    #pragma unroll
    for (int kk = 0; kk < 4; ++kk){
      int cb = (kk*64 + g*16) ^ ((l15&7)<<4);
      short8 xm[2], xx[2];
      xm[0] = ldfrag(lds + XMS_OFF + l15*256 + cb);
      xm[1] = ldfrag(lds + XMS_OFF + (16+l15)*256 + cb);
      xx[0] = ldfrag(lds + XS_OFF + l15*256 + cb);
      xx[1] = ldfrag(lds + XS_OFF + (16+l15)*256 + cb);
      #pragma unroll
      for (int n = 0; n < 2; ++n){
        size_t wrow = (size_t)(w*32 + n*16 + l15)*128 + kk*32 + g*8;
        short8 wgf  = *reinterpret_cast<const short8*>(WGb  + wrow);
        short8 wg1f = *reinterpret_cast<const short8*>(WG1b + wrow);
        #pragma unroll
        for (int mt = 0; mt < 2; ++mt){
          ah[mt][n] = __builtin_amdgcn_mfma_f32_16x16x32_bf16(xm[mt], wgf,  ah[mt][n], 0, 0, 0);
          ah[mt][n] = __builtin_amdgcn_mfma_f32_16x16x32_bf16(xx[mt], wg1f, ah[mt][n], 0, 0, 0);
        }
      }
    }

    // ---- epilogue: per-channel running sum/sumsq (j<25) + per-token extreme ----
    #pragma unroll
    for (int n = 0; n < 2; ++n){
      float e = sg[n] ? -3.0e38f : 3.0e38f;
      #pragma unroll
      for (int mt = 0; mt < 2; ++mt)
        #pragma unroll
        for (int r = 0; r < 4; ++r){
          int row = mt*16 + g*4 + r;
          if (row < 25){
            float v = ah[mt][n][r];
            rs[n] += v; rq[n] += v*v;
            e = sg[n] ? fmaxf(e, v) : fminf(e, v);
          }
        }
      float e2 = __shfl_xor(e, 16);
      e = sg[n] ? fmaxf(e, e2) : fminf(e, e2);
      e2 = __shfl_xor(e, 32);
      e = sg[n] ? fmaxf(e, e2) : fminf(e, e2);
      if (g == 0) ext[(size_t)token*256 + oc_[n]] = e;
    }
    __syncthreads();
  }

  // ---- block partials for BN2 stats ----
  #pragma unroll
  for (int n = 0; n < 2; ++n){
    float s = rs[n], q = rq[n];
    s += __shfl_xor(s, 16); s += __shfl_xor(s, 32);
    q += __shfl_xor(q, 16); q += __shfl_xor(q, 32);
    if (g == 0){
      partials[(size_t)blockIdx.x*512 + oc_[n]]       = s;
      partials[(size_t)blockIdx.x*512 + 256 + oc_[n]] = q;
    }
  }
}

// ---------------- BN2 finalize: per-channel scale/bias ----------------
__global__ void kbn2(const float* __restrict__ partials,
                     const float* __restrict__ gg, const float* __restrict__ gb,
                     float* sb)
{
  __shared__ float red[256];
  __shared__ float red2[256];
  int oc = blockIdx.x, tid = threadIdx.x;
  float s = 0.f, q = 0.f;
  for (int i = tid; i < 2048; i += 256){
    s += partials[(size_t)i*512 + oc];
    q += partials[(size_t)i*512 + 256 + oc];
  }
  red[tid] = s; red2[tid] = q;
  __syncthreads();
  for (int off = 128; off > 0; off >>= 1){
    if (tid < off){ red[tid] += red[tid+off]; red2[tid] += red2[tid+off]; }
    __syncthreads();
  }
  if (tid == 0){
    float m = red[0] * (1.f/409600.f);
    float v = red2[0] * (1.f/409600.f) - m*m;
    float rstd = rsqrtf(v + 1e-5f);
    float sc = gg[oc]*rstd;
    sb[oc*2]   = sc;
    sb[oc*2+1] = gb[oc] - m*sc;
  }
}

// ---------------- pass2: out[b][oc][t] = relu(scale*ext + bias), LDS transpose ----
__global__ void kpass2(const float* __restrict__ ext, const float* __restrict__ sb,
                       float* __restrict__ out)
{
  __shared__ float st[32][257];
  int b = blockIdx.x >> 4, tc = blockIdx.x & 15;
  int t0 = tc*32, tid = threadIdx.x;
  for (int i = tid; i < 32*256; i += 256){
    int tt = i >> 8, oc = i & 255;
    float v = ext[((size_t)(b*512) + t0 + tt)*256 + oc];
    st[tt][oc] = fmaxf(v*sb[oc*2] + sb[oc*2+1], 0.f);
  }
  __syncthreads();
  for (int i = tid; i < 32*256; i += 256){
    int oc = i >> 5, tt = i & 31;
    out[((size_t)(b*256) + oc)*512 + t0 + tt] = st[tt][oc];
  }
}

extern "C" void kernel_launch(void* const* d_in, const int* in_sizes, int n_in,
                              void* d_out, int out_size, void* d_ws, size_t ws_size,
                              hipStream_t stream)
{
  (void)in_sizes; (void)n_in; (void)out_size; (void)ws_size;
  const float* Angle = (const float*)d_in[0];
  const float* dif   = (const float*)d_in[1];
  const float* spa   = (const float*)d_in[2];
  const float* je_g  = (const float*)d_in[3];
  const float* je_b  = (const float*)d_in[4];
  const float* je_w1 = (const float*)d_in[5];
  const float* je_b1 = (const float*)d_in[6];
  const float* je_w2 = (const float*)d_in[7];
  const float* je_b2 = (const float*)d_in[8];
  const float* df_g  = (const float*)d_in[9];
  const float* df_b  = (const float*)d_in[10];
  const float* df_w1 = (const float*)d_in[11];
  const float* df_b1 = (const float*)d_in[12];
  const float* df_w2 = (const float*)d_in[13];
  const float* df_b2 = (const float*)d_in[14];
  const float* sp_w1 = (const float*)d_in[15];
  const float* sp_b1 = (const float*)d_in[16];
  const float* sp_w2 = (const float*)d_in[17];
  const float* sp_b2 = (const float*)d_in[18];
  const float* g1_w  = (const float*)d_in[19];
  const float* g1_b  = (const float*)d_in[20];
  const float* g2_w  = (const float*)d_in[21];
  const float* g2_b  = (const float*)d_in[22];
  const float* gw    = (const float*)d_in[23];
  const float* gw1   = (const float*)d_in[24];
  const float* gw1_b = (const float*)d_in[25];
  const float* gbn_g = (const float*)d_in[26];
  const float* gbn_b = (const float*)d_in[27];

  char* ws = (char*)d_ws;
  float* sbA     = (float*)(ws + OFF_SBA);
  float* sbD     = (float*)(ws + OFF_SBD);
  float* spa_arr = (float*)(ws + OFF_SPA);
  float* w2aT    = (float*)(ws + OFF_W2AT);
  float* w2dT    = (float*)(ws + OFF_W2DT);
  float* bn2sb   = (float*)(ws + OFF_BN2SB);
  __hip_bfloat16* W1b  = (__hip_bfloat16*)(ws + OFF_W1B);
  __hip_bfloat16* W2b  = (__hip_bfloat16*)(ws + OFF_W2B);
  __hip_bfloat16* WGb  = (__hip_bfloat16*)(ws + OFF_WGB);
  __hip_bfloat16* WG1b = (__hip_bfloat16*)(ws + OFF_WG1B);
  float* partials = (float*)(ws + OFF_PART);
  float* ext      = (float*)(ws + OFF_EXT);
  __hip_bfloat16* inp = (__hip_bfloat16*)(ws + OFF_INP);

  kprep<<<128, 256, 0, stream>>>(g1_w, g2_w, gw, gw1, je_w2, df_w2,
                                 W1b, W2b, WGb, WG1b, w2aT, w2dT);
  kspa<<<1, 256, 0, stream>>>(sp_w1, sp_b1, sp_w2, sp_b2, spa, spa_arr);
  kbn1<<<150, 256, 0, stream>>>(Angle, dif, je_g, je_b, df_g, df_b, sbA, sbD);
  kembed<<<dim3(32, 25, 2), 256, 0, stream>>>(Angle, dif, sbA, sbD,
                                              je_w1, je_b1, w2aT, je_b2,
                                              df_w1, df_b1, w2dT, df_b2,
                                              spa_arr, inp);
  kattn<<<2048, 512, 0, stream>>>((const unsigned short*)inp, W1b, W2b, WGb, WG1b,
                                  g1_b, g2_b, gw1_b, gbn_g, ext, partials);
  kbn2<<<256, 256, 0, stream>>>(partials, gbn_g, gbn_b, bn2sb);
  kpass2<<<512, 256, 0, stream>>>(ext, bn2sb, (float*)d_out);
}